// Round 1
// baseline (415.946 us; speedup 1.0000x reference)
//
#include <hip/hip_runtime.h>
#include <math.h>

// Problem constants (fixed by setup_inputs)
#define BB 512
#define CC 480              // C1*C2 = 16*30 channels per batch
#define HW 225              // 15*15 pixels per channel
#define CHW (CC * HW)       // 108000 floats per batch
#define NF4 (CHW / 4)       // 27000 float4 per batch
#define NGRP (CC / 4)       // 120 groups of 4 channels (900 floats = 225 f4)
#define NGRP_TOTAL (BB * NGRP)  // 61440 groups over the whole tensor

// Kernel A (reduce): 1920 blocks x 256 thr = 7680 waves, exactly 8 groups/wave.
#define RED_BLOCKS 1920
#define RED_THREADS 256
#define RED_WAVES (RED_BLOCKS * (RED_THREADS / 64))

// Kernel C (scale): 8 chunks per batch, 60 whole channels per chunk.
#define CHUNKS 8
#define CHUNK_F4 (NF4 / CHUNKS)   // 3375 float4 per chunk
#define CHUNK_CH (CC / CHUNKS)    // 60 channels per chunk (13500/225)
#define SC_THREADS 256
#define SC_FULL_ITERS (CHUNK_F4 / SC_THREADS)        // 13
#define SC_TAIL (CHUNK_F4 - SC_FULL_ITERS * SC_THREADS)  // 47

using f4 = __attribute__((ext_vector_type(4))) float;

__device__ __forceinline__ float sigmoidf(float v) {
    return 1.0f / (1.0f + __expf(-v));
}

// ---------------------------------------------------------------------------
// Kernel A: per-channel full & center-3x3 sums. Pure HBM read stream, no
// barriers, occupancy-filling grid (7680 waves, 8 groups each, uniform work).
// Writes per-channel means to workspace S (full) and R (ring).
// ---------------------------------------------------------------------------
__global__ __launch_bounds__(RED_THREADS) void reduce_kernel(
    const float* __restrict__ x,
    float* __restrict__ S, float* __restrict__ R)
{
    const int wave = threadIdx.x >> 6;
    const int lane = threadIdx.x & 63;
    const int gw0 = blockIdx.x * (RED_THREADS / 64) + wave;

    for (int gg = gw0; gg < NGRP_TOTAL; gg += RED_WAVES) {
        const int b  = gg / NGRP;          // magic-mul
        const int gr = gg - b * NGRP;
        const f4* __restrict__ gp = (const f4*)x + (long long)b * NF4 + gr * 225;

        float f0 = 0.f, f1 = 0.f, f2 = 0.f, f3 = 0.f;
        float r0 = 0.f, r1 = 0.f, r2 = 0.f, r3 = 0.f;
#pragma unroll
        for (int j = 0; j < 4; ++j) {
            const int idx = lane + 64 * j;
            if (idx < 225) {
                f4 v = gp[idx];
                const int e0 = 4 * idx;
#pragma unroll
                for (int jj = 0; jj < 4; ++jj) {
                    const int e = e0 + jj;                    // 0..899
                    const float vv = v[jj];
                    const int q = (e >= 450) ? ((e >= 675) ? 3 : 2)
                                             : ((e >= 225) ? 1 : 0);
                    const int r = e - 225 * q;                // 0..224
                    const bool ring = (r >= 96 && r <= 98) ||
                                      (r >= 111 && r <= 113) ||
                                      (r >= 126 && r <= 128);
                    const float rv = ring ? vv : 0.f;
                    f0 += (q == 0) ? vv : 0.f;
                    f1 += (q == 1) ? vv : 0.f;
                    f2 += (q == 2) ? vv : 0.f;
                    f3 += (q == 3) ? vv : 0.f;
                    r0 += (q == 0) ? rv : 0.f;
                    r1 += (q == 1) ? rv : 0.f;
                    r2 += (q == 2) ? rv : 0.f;
                    r3 += (q == 3) ? rv : 0.f;
                }
            }
        }
#pragma unroll
        for (int off = 32; off > 0; off >>= 1) {
            f0 += __shfl_down(f0, off, 64);
            f1 += __shfl_down(f1, off, 64);
            f2 += __shfl_down(f2, off, 64);
            f3 += __shfl_down(f3, off, 64);
            r0 += __shfl_down(r0, off, 64);
            r1 += __shfl_down(r1, off, 64);
            r2 += __shfl_down(r2, off, 64);
            r3 += __shfl_down(r3, off, 64);
        }
        if (lane == 0) {
            const float s = 1.0f / 225.0f;
            const int base = b * CC + 4 * gr;
            S[base + 0] = f0 * s;  R[base + 0] = r0 * s;
            S[base + 1] = f1 * s;  R[base + 1] = r1 * s;
            S[base + 2] = f2 * s;  R[base + 2] = r2 * s;
            S[base + 3] = f3 * s;  R[base + 3] = r3 * s;
        }
    }
}

// ---------------------------------------------------------------------------
// Kernel B: per-channel gates from the means (983 KB in, 983 KB out — tiny).
// Same math as the verified phase-2 of the fused kernel.
// ---------------------------------------------------------------------------
__global__ __launch_bounds__(512) void gate_kernel(
    const float* __restrict__ S, const float* __restrict__ R,
    const float* __restrict__ w1, const float* __restrict__ b1,
    const float* __restrict__ w2, const float* __restrict__ b2,
    float* __restrict__ G)
{
    const int b = blockIdx.x;
    const int c = threadIdx.x;
    if (c < CC) {
        const float* __restrict__ Ms = S + b * CC;
        const float* __restrict__ Rs = R + b * CC;
        float g1 = b1[0], g2 = b2[0];
#pragma unroll
        for (int k = 0; k < 5; ++k) {
            const int j = c + k - 2;
            if (j >= 0 && j < CC) {
                g1 += w1[k] * Ms[j] + w1[5 + k] * Ms[CC - 1 - j];
                g2 += w2[k] * Rs[j] + w2[5 + k] * Rs[CC - 1 - j];
            }
        }
        G[b * CC + c] = sigmoidf((sigmoidf(g1) * sigmoidf(g2) - 0.2f) * 2.0f);
    }
}

// ---------------------------------------------------------------------------
// Kernel C: streaming scale. One block per (batch, 60-channel chunk); chunk
// boundaries coincide with channel boundaries (13500 = 60*225), so a block's
// gates fit in a 60-float LDS array. x re-read hits L3 (warmed by kernel A);
// nontemporal stores keep the output stream from evicting x.
// ---------------------------------------------------------------------------
__global__ __launch_bounds__(SC_THREADS) void scale_kernel(
    const float* __restrict__ x, const float* __restrict__ G,
    float* __restrict__ out)
{
    __shared__ float As[CHUNK_CH];
    const int blk = blockIdx.x;
    const int b = blk >> 3;          // CHUNKS == 8
    const int s = blk & 7;
    const int t = threadIdx.x;

    if (t < CHUNK_CH) As[t] = G[b * CC + s * CHUNK_CH + t];
    __syncthreads();

    const f4* __restrict__ xb = (const f4*)x + (long long)b * NF4 + s * CHUNK_F4;
    f4* __restrict__ ob = (f4*)out + (long long)b * NF4 + s * CHUNK_F4;

#pragma unroll 4
    for (int k = 0; k < SC_FULL_ITERS; ++k) {
        const int g = t + SC_THREADS * k;
        f4 v = xb[g];
        const int e = 4 * g;               // 0..13499, chunk-local
        const int c = e / 225;             // magic-mul; 0..59
        const int rr = e - 225 * c;
        v[0] *= As[c];
        v[1] *= As[c + (rr >= 224)];
        v[2] *= As[c + (rr >= 223)];
        v[3] *= As[c + (rr >= 222)];
        __builtin_nontemporal_store(v, &ob[g]);
    }
    // tail: 3375 = 13*256 + 47
    if (t < SC_TAIL) {
        const int g = SC_FULL_ITERS * SC_THREADS + t;
        f4 v = xb[g];
        const int e = 4 * g;
        const int c = e / 225;
        const int rr = e - 225 * c;
        v[0] *= As[c];
        v[1] *= As[c + (rr >= 224)];
        v[2] *= As[c + (rr >= 223)];
        v[3] *= As[c + (rr >= 222)];
        __builtin_nontemporal_store(v, &ob[g]);
    }
}

extern "C" void kernel_launch(void* const* d_in, const int* in_sizes, int n_in,
                              void* d_out, int out_size, void* d_ws, size_t ws_size,
                              hipStream_t stream)
{
    const float* x  = (const float*)d_in[0];
    const float* w1 = (const float*)d_in[1];
    const float* b1 = (const float*)d_in[2];
    const float* w2 = (const float*)d_in[3];
    const float* b2 = (const float*)d_in[4];
    float* out = (float*)d_out;

    float* S = (float*)d_ws;          // [BB][CC] full means
    float* R = S + BB * CC;           // [BB][CC] ring means
    float* G = R + BB * CC;           // [BB][CC] gates
    // total workspace: 3 * 512 * 480 * 4 B = 2.95 MB

    reduce_kernel<<<RED_BLOCKS, RED_THREADS, 0, stream>>>(x, S, R);
    gate_kernel<<<BB, 512, 0, stream>>>(S, R, w1, b1, w2, b2, G);
    scale_kernel<<<BB * CHUNKS, SC_THREADS, 0, stream>>>(x, G, out);
}